// Round 5
// baseline (684.458 us; speedup 1.0000x reference)
//
#include <hip/hip_runtime.h>
#include <math.h>

#define T_SEQ 4096
#define HD 128
#define NH 4
#define DS 512
#define SCALE 0.08838834764831845f
#define NEG9 (-1.0e9f)
#define BN 32
#define VT_STRIDE 4096
#define NCH 128   // T_SEQ / BN
#define NRT 256   // T_SEQ / 16

typedef __attribute__((ext_vector_type(8))) _Float16 half8;
typedef __attribute__((ext_vector_type(4))) float floatx4;

__device__ __forceinline__ float sigmoidf_(float x) {
  if (x >= 0.0f) return 1.0f / (1.0f + expf(-x));
  float e = expf(x);
  return e / (1.0f + e);
}

// ---------------- fp32 -> fp16 split convert (Q, K): h + e residual ----------------
__global__ __launch_bounds__(256) void cvt2_kernel(const float* __restrict__ src,
                                                   _Float16* __restrict__ dh,
                                                   _Float16* __restrict__ de, int nelem) {
  int idx = (blockIdx.x * 256 + threadIdx.x) * 8;
  if (idx >= nelem) return;
  float4 a = *(const float4*)&src[idx];
  float4 b = *(const float4*)&src[idx + 4];
  float v[8] = {a.x, a.y, a.z, a.w, b.x, b.y, b.z, b.w};
  half8 oh, oe;
#pragma unroll
  for (int t = 0; t < 8; ++t) {
    _Float16 hh = (_Float16)v[t];
    oh[t] = hh;
    oe[t] = (_Float16)(v[t] - (float)hh);
  }
  *(half8*)&dh[idx] = oh;
  *(half8*)&de[idx] = oe;
}

// ---------------- V -> Vt (transposed, fp16) ----------------
__global__ __launch_bounds__(256) void vt_kernel(const float* __restrict__ V,
                                                 _Float16* __restrict__ Vt) {
  __shared__ float tile[32][33];
  int h = blockIdx.z, dt = blockIdx.y, jt = blockIdx.x;
  int tx = threadIdx.x, ty = threadIdx.y;
  for (int k = 0; k < 4; ++k) {
    int row = jt * 32 + ty + k * 8;
    tile[ty + k * 8][tx] = V[((h * T_SEQ) + row) * HD + dt * 32 + tx];
  }
  __syncthreads();
  for (int k = 0; k < 4; ++k) {
    int d = dt * 32 + ty + k * 8;
    int j = jt * 32 + tx;
    Vt[((size_t)(h * HD) + d) * VT_STRIDE + j] = (_Float16)tile[tx][ty + k * 8];
  }
}

// ---------------- Kernel A: downsampled scores (fp32, bit-stable) ----------------
__global__ __launch_bounds__(256) void sds_kernel(const float* __restrict__ Q,
                                                  const float* __restrict__ K,
                                                  float* __restrict__ sds) {
  __shared__ float Qs[16][132];
  __shared__ float Ks[16][132];
  const int h = blockIdx.z;
  const int by = blockIdx.y, bx = blockIdx.x;
  const int tid = threadIdx.y * 16 + threadIdx.x;
  for (int t = tid; t < 512; t += 256) {
    int r = t >> 5, f = (t & 31) * 4;
    *(float4*)&Qs[r][f] = *(const float4*)&Q[((h * T_SEQ) + (by * 16 + r) * 8) * HD + f];
    *(float4*)&Ks[r][f] = *(const float4*)&K[((h * T_SEQ) + (bx * 16 + r) * 8) * HD + f];
  }
  __syncthreads();
  const int ty = threadIdx.y, tx = threadIdx.x;
  float acc = 0.0f;
  for (int k = 0; k < 32; ++k) {
    float4 a = *(float4*)&Qs[ty][k * 4];
    float4 b = *(float4*)&Ks[tx][k * 4];
    acc += a.x * b.x + a.y * b.y + a.z * b.z + a.w * b.w;
  }
  sds[((h * DS) + by * 16 + ty) * DS + bx * 16 + tx] = acc * SCALE;
}

// ---------------- Kernel B: exact 128th-largest per ds-row ----------------
__global__ __launch_bounds__(64) void thr_kernel(const float* __restrict__ sds,
                                                 float* __restrict__ thr) {
  const int row = blockIdx.x;
  const int lane = threadIdx.x;
  unsigned v[8];
  for (int t = 0; t < 8; ++t) {
    float f = sds[row * DS + t * 64 + lane];
    unsigned b = __float_as_uint(f);
    v[t] = (b & 0x80000000u) ? ~b : (b | 0x80000000u);
  }
  unsigned prefix = 0u;
  for (int bit = 31; bit >= 0; --bit) {
    unsigned cand = prefix | (1u << bit);
    int c = 0;
    for (int t = 0; t < 8; ++t) c += (v[t] >= cand) ? 1 : 0;
    for (int off = 32; off > 0; off >>= 1) c += __shfl_down(c, off, 64);
    c = __shfl(c, 0, 64);
    if (c >= 128) prefix = cand;
  }
  if (lane == 0) {
    unsigned b = (prefix & 0x80000000u) ? (prefix ^ 0x80000000u) : ~prefix;
    thr[row] = __uint_as_float(b);
  }
}

// ---------------- Kernel B2: per (h, row-tile16, chunk32) bias max ----------------
// bias sequence is bit-identical to the attention kernel's.
__global__ __launch_bounds__(256) void bmax_kernel(const float* __restrict__ sds,
                                                   const float* __restrict__ thr,
                                                   const float* __restrict__ U,
                                                   float* __restrict__ bmax16) {
  const int h = blockIdx.y, rt = blockIdx.x;
  const int tid = threadIdx.x, ww = tid >> 6, lane = tid & 63;
  const int r = lane >> 2, q = lane & 3;
  const int i = rt * 16 + r;
  float u = U[i];
  u = fminf(fmaxf(u, 0.0f), 1.0f);
  const float us = 1.0f + u;
  const int id = i >> 3;
  const float bb = us * thr[h * DS + id];
  const float* srow = &sds[((h * DS) + id) * DS];
  for (int c = ww; c < NCH; c += 4) {
    float sval = srow[(c << 2) + q];
    float a = us * sval;
    float bias = (1.0f - sigmoidf_((a - bb) * 10.0f)) * NEG9;
    for (int off = 1; off < 64; off <<= 1)
      bias = fmaxf(bias, __shfl_xor(bias, off, 64));
    if (lane == 0) bmax16[((h * NRT) + rt) * NCH + c] = bias;
  }
}

// ---------------- Kernel C: MFMA flash attention, planned hot/cold sweeps ----------------
// 4 waves/block, 16 rows. Wave w owns chunks c = w + 4*cc. Hot set planned from
// bmax16 via one ballot; cold chunks m-checked cheaply in sweep 1.
// QK uses 3-term fp16 split (Qh·Kh + Qe·Kh + Qh·Ke) to kill fp16 rounding error.
__global__ __launch_bounds__(256) void attn4_kernel(
    const _Float16* __restrict__ Qh, const _Float16* __restrict__ Qe,
    const _Float16* __restrict__ Kh, const _Float16* __restrict__ Ke,
    const _Float16* __restrict__ Vt, const float* __restrict__ Vf,
    const float* __restrict__ U, const float* __restrict__ sds,
    const float* __restrict__ thr, const float* __restrict__ bmax16,
    float* __restrict__ out) {
  const int h = blockIdx.y;
  const int ib = (int)gridDim.x - 1 - (int)blockIdx.x;  // heavy blocks first
  const int i0 = ib * 16;
  const int tid = threadIdx.x;
  const int w = tid >> 6;
  const int lane = tid & 63;
  const int quad = lane >> 4;
  const int n = lane & 15;

  __shared__ float Obuf[4][16][128];
  __shared__ _Float16 Ps[4][16][32];
  __shared__ float mW[4][16], lW[4][16];
  __shared__ float VtailS[2][128];
  __shared__ int deadFlag;

  if (tid == 0) deadFlag = 0;

  // per-row constants (rows quad*4+r); 4 rows of a quad share one ds-row
  const int myid = (i0 >> 3) + (quad >> 1);
  float us[4], bb[4];
  for (int r = 0; r < 4; ++r) {
    int i = i0 + quad * 4 + r;
    float u = U[i];
    u = fminf(fmaxf(u, 0.0f), 1.0f);
    us[r] = 1.0f + u;
    bb[r] = us[r] * thr[h * DS + myid];
  }

  // Q A-fragments, main + residual
  half8 qfh[4], qfe[4];
  {
    const size_t qoff = (size_t)((h * T_SEQ) + i0 + n) * HD + quad * 8;
#pragma unroll
    for (int d = 0; d < 4; ++d) {
      qfh[d] = *(const half8*)&Qh[qoff + d * 32];
      qfe[d] = *(const half8*)&Qe[qoff + d * 32];
    }
  }

  floatx4 acc[8];
  for (int t = 0; t < 8; ++t) acc[t] = (floatx4){0.f, 0.f, 0.f, 0.f};
  float m_[4], l_[4];
  for (int r = 0; r < 4; ++r) { m_[r] = -INFINITY; l_[r] = 0.0f; }

  const int nchunks = i0 / BN + 1;
  const int nMine = (nchunks > w) ? ((nchunks - w + 3) >> 2) : 0;

  // ---- planning: one load + one ballot gives the static hot set ----
  float bval = -3.0e38f;
  if (lane < nMine)
    bval = bmax16[((h * NRT) + ib) * NCH + (w + (lane << 2))];
  const unsigned long long laneBits = (nMine >= 64) ? ~0ull : ((1ull << nMine) - 1ull);
  const unsigned long long hotMask = __ballot(lane < nMine && bval > -124.0f) & laneBits;
  const unsigned long long coldMask = laneBits & ~hotMask;

#pragma unroll 2
  for (int sweep = 0; sweep < 2; ++sweep) {
    unsigned long long mask = (sweep == 0) ? hotMask : coldMask;
    while (mask) {
      const int cc = __builtin_ctzll(mask);
      mask &= mask - 1ull;
      if (sweep == 1) {
        // cheap m-based skip: bmax16 >= per-row bmax, mmin <= per-row m  => safe
        float bm16 = __shfl(bval, cc, 64);
        float mm = fminf(fminf(m_[0], m_[1]), fminf(m_[2], m_[3]));
        mm = fminf(mm, __shfl_xor(mm, 16, 64));
        mm = fminf(mm, __shfl_xor(mm, 32, 64));
        if (bm16 + 12.0f < mm - 40.0f) continue;
      }
      const int c = w + (cc << 2);
      const int j0 = c * BN;

      // ---- bias: bit-identical fp32 sequence ----
      const int jdA = (c << 2) + (n >> 3);
      const float svA = sds[((h * DS) + myid) * DS + jdA];
      const float svB = sds[((h * DS) + myid) * DS + jdA + 2];
      float biasA[4], biasB[4];
      for (int r = 0; r < 4; ++r) {
        float aA = us[r] * svA;
        biasA[r] = (1.0f - sigmoidf_((aA - bb[r]) * 10.0f)) * NEG9;
        float aB = us[r] * svB;
        biasB[r] = (1.0f - sigmoidf_((aB - bb[r]) * 10.0f)) * NEG9;
      }

      // ---- K loads (both col-tiles, main + residual) ----
      const size_t kbase = (size_t)((h * T_SEQ) + j0 + n) * HD + quad * 8;
      half8 kh0[4], ke0[4], kh1[4], ke1[4];
#pragma unroll
      for (int d = 0; d < 4; ++d) {
        kh0[d] = *(const half8*)&Kh[kbase + d * 32];
        ke0[d] = *(const half8*)&Ke[kbase + d * 32];
        kh1[d] = *(const half8*)&Kh[kbase + 16 * HD + d * 32];
        ke1[d] = *(const half8*)&Ke[kbase + 16 * HD + d * 32];
      }

      // ---- QK^T: 3-term split, 24 mfma ----
      floatx4 S0 = (floatx4){0.f, 0.f, 0.f, 0.f};
      floatx4 S1 = (floatx4){0.f, 0.f, 0.f, 0.f};
#pragma unroll
      for (int d = 0; d < 4; ++d) {
        S0 = __builtin_amdgcn_mfma_f32_16x16x32_f16(qfh[d], kh0[d], S0, 0, 0, 0);
        S1 = __builtin_amdgcn_mfma_f32_16x16x32_f16(qfh[d], kh1[d], S1, 0, 0, 0);
      }
#pragma unroll
      for (int d = 0; d < 4; ++d) {
        S0 = __builtin_amdgcn_mfma_f32_16x16x32_f16(qfe[d], kh0[d], S0, 0, 0, 0);
        S1 = __builtin_amdgcn_mfma_f32_16x16x32_f16(qfe[d], kh1[d], S1, 0, 0, 0);
        S0 = __builtin_amdgcn_mfma_f32_16x16x32_f16(qfh[d], ke0[d], S0, 0, 0, 0);
        S1 = __builtin_amdgcn_mfma_f32_16x16x32_f16(qfh[d], ke1[d], S1, 0, 0, 0);
      }

      // ---- scores & online softmax (fast exp; endpoints exact) ----
      const int jA = j0 + n, jB = j0 + 16 + n;
      float sc0[4], sc1[4];
      for (int r = 0; r < 4; ++r) {
        int i = i0 + quad * 4 + r;
        sc0[r] = (jA <= i) ? (S0[r] * SCALE + biasA[r]) : NEG9;
        sc1[r] = (jB <= i) ? (S1[r] * SCALE + biasB[r]) : NEG9;
      }
      float mx[4];
      for (int r = 0; r < 4; ++r) mx[r] = fmaxf(sc0[r], sc1[r]);
      for (int d = 1; d < 16; d <<= 1)
        for (int r = 0; r < 4; ++r) mx[r] = fmaxf(mx[r], __shfl_xor(mx[r], d, 64));
      float alpha[4], lsum[4];
      _Float16 ph0[4], ph1[4];
      for (int r = 0; r < 4; ++r) {
        float mnew = fmaxf(m_[r], mx[r]);
        alpha[r] = __expf(m_[r] - mnew);  // -inf -> 0
        ph0[r] = (_Float16)__expf(sc0[r] - mnew);
        ph1[r] = (_Float16)__expf(sc1[r] - mnew);
        lsum[r] = (float)ph0[r] + (float)ph1[r];  // l consistent with PV numerator
        m_[r] = mnew;
      }
      for (int d = 1; d < 16; d <<= 1)
        for (int r = 0; r < 4; ++r) lsum[r] += __shfl_xor(lsum[r], d, 64);
      for (int r = 0; r < 4; ++r) l_[r] = l_[r] * alpha[r] + lsum[r];
      for (int t = 0; t < 8; ++t)
        for (int r = 0; r < 4; ++r) acc[t][r] *= alpha[r];

      // ---- P: C-layout -> A-layout via wave-private LDS ----
      for (int r = 0; r < 4; ++r) {
        Ps[w][quad * 4 + r][n] = ph0[r];
        Ps[w][quad * 4 + r][n + 16] = ph1[r];
      }
      __builtin_amdgcn_sched_barrier(0);
      __builtin_amdgcn_s_waitcnt(0xC07F);  // lgkmcnt(0) only
      __builtin_amdgcn_sched_barrier(0);
      half8 pf = *(half8*)&Ps[w][n][quad * 8];

      // ---- P @ V ----
      const _Float16* vbase = &Vt[(size_t)((h * HD) + n) * VT_STRIDE + j0 + quad * 8];
#pragma unroll
      for (int t = 0; t < 8; ++t) {
        half8 vf = *(const half8*)&vbase[(size_t)t * 16 * VT_STRIDE];
        acc[t] = __builtin_amdgcn_mfma_f32_16x16x32_f16(pf, vf, acc[t], 0, 0, 0);
      }
    }
  }

  // ---- merge per-wave states (round-4 structure, unchanged) ----
  if (n == 0) {
    for (int r = 0; r < 4; ++r) {
      mW[w][quad * 4 + r] = m_[r];
      lW[w][quad * 4 + r] = l_[r];
    }
  }
  for (int t = 0; t < 8; ++t)
    for (int r = 0; r < 4; ++r) Obuf[w][quad * 4 + r][t * 16 + n] = acc[t][r];
  __syncthreads();

  if (tid < 16) {
    float M = fmaxf(fmaxf(mW[0][tid], mW[1][tid]), fmaxf(mW[2][tid], mW[3][tid]));
    if (M < -1.0e8f) atomicOr(&deadFlag, 1);
  }
  __syncthreads();

  const int jcov = BN * nchunks;
  if (deadFlag) {
    int d = tid & 127, hlf = tid >> 7;
    float s = 0.f;
    for (int j = jcov + hlf; j < T_SEQ; j += 2)
      s += Vf[(size_t)((h * T_SEQ) + j) * HD + d];
    VtailS[hlf][d] = s;
  }
  __syncthreads();

  const float n_nc = (float)(T_SEQ - jcov);
  for (int idx = tid; idx < 16 * 128; idx += 256) {
    int r = idx >> 7, d = idx & 127;
    float M = fmaxf(fmaxf(mW[0][r], mW[1][r]), fmaxf(mW[2][r], mW[3][r]));
    float e0 = expf(mW[0][r] - M), e1 = expf(mW[1][r] - M);
    float e2 = expf(mW[2][r] - M), e3 = expf(mW[3][r] - M);
    float L = lW[0][r] * e0 + lW[1][r] * e1 + lW[2][r] * e2 + lW[3][r] * e3;
    float wdead = expf(NEG9 - M);  // ==1 iff row fully dead, else 0
    L += n_nc * wdead;
    float o = Obuf[0][r][d] * e0 + Obuf[1][r][d] * e1 + Obuf[2][r][d] * e2 +
              Obuf[3][r][d] * e3;
    if (deadFlag) o += wdead * (VtailS[0][d] + VtailS[1][d]);
    out[(size_t)((h * T_SEQ) + i0 + r) * HD + d] = o / L;
  }
}

extern "C" void kernel_launch(void* const* d_in, const int* in_sizes, int n_in,
                              void* d_out, int out_size, void* d_ws, size_t ws_size,
                              hipStream_t stream) {
  const float* Q = (const float*)d_in[0];
  const float* K = (const float*)d_in[1];
  const float* V = (const float*)d_in[2];
  const float* U = (const float*)d_in[3];
  float* out = (float*)d_out;

  char* wsb = (char*)d_ws;
  float* sds = (float*)wsb;                              // 4 MB
  float* thr = (float*)(wsb + 4194304);                  // 8 KB
  float* bmax16 = (float*)(wsb + 4194304 + 8192);        // 512 KB
  _Float16* Qh = (_Float16*)(wsb + 4194304 + 8192 + 524288);
  _Float16* Qe = Qh + 2097152;
  _Float16* Kh = Qe + 2097152;
  _Float16* Ke = Kh + 2097152;
  _Float16* Vt = Ke + 2097152;                           // total ~24.5 MB

  const int nQK = NH * T_SEQ * HD;  // 2,097,152
  cvt2_kernel<<<nQK / 2048, 256, 0, stream>>>(Q, Qh, Qe, nQK);
  cvt2_kernel<<<nQK / 2048, 256, 0, stream>>>(K, Kh, Ke, nQK);
  vt_kernel<<<dim3(T_SEQ / 32, HD / 32, NH), dim3(32, 8), 0, stream>>>(V, Vt);

  sds_kernel<<<dim3(DS / 16, DS / 16, NH), dim3(16, 16), 0, stream>>>(Q, K, sds);
  thr_kernel<<<NH * DS, 64, 0, stream>>>(sds, thr);
  bmax_kernel<<<dim3(NRT, NH), 256, 0, stream>>>(sds, thr, U, bmax16);

  attn4_kernel<<<dim3(NRT, NH), 256, 0, stream>>>(Qh, Qe, Kh, Ke, Vt, V, U, sds, thr,
                                                  bmax16, out);
}

// Round 6
// 492.455 us; speedup vs baseline: 1.3899x; 1.3899x over previous
//
#include <hip/hip_runtime.h>
#include <math.h>

#define T_SEQ 4096
#define HD 128
#define NH 4
#define DS 512
#define SCALE 0.08838834764831845f
#define NEG9 (-1.0e9f)
#define BN 32
#define VT_STRIDE 4096
#define NCH 128        // T_SEQ / BN
#define NRT 256        // T_SEQ / 16
#define SEGC 32        // chunks per j-segment
#define PART_F 2080    // floats per partial: 16 m + 16 l + 16*128 O
#define NPART_H 640    // sum over rt of ns(rt) = rt/64+1
#define ALIVE_MIN (-999999936.0f)  // smallest fp32 score an alive row can have

typedef __attribute__((ext_vector_type(8))) _Float16 half8;
typedef __attribute__((ext_vector_type(4))) float floatx4;

__device__ __host__ inline int tile_base(int rt) {  // sum of ns(r) for r < rt
  int a = rt >> 6, b = rt & 63;
  return rt + 32 * a * (a - 1) + a * b;
}

__device__ __forceinline__ float sigmoidf_(float x) {
  if (x >= 0.0f) return 1.0f / (1.0f + expf(-x));
  float e = expf(x);
  return e / (1.0f + e);
}

// ---------------- fp32 -> fp16 split convert: Q and K in one launch ----------------
__global__ __launch_bounds__(256) void cvt2_kernel(const float* __restrict__ Q,
                                                   const float* __restrict__ K,
                                                   _Float16* __restrict__ Qh,
                                                   _Float16* __restrict__ Qe,
                                                   _Float16* __restrict__ Kh,
                                                   _Float16* __restrict__ Ke, int nelem) {
  int idx = (blockIdx.x * 256 + threadIdx.x) * 8;
  if (idx >= nelem) return;
  const float* src = blockIdx.y ? K : Q;
  _Float16* dh = blockIdx.y ? Kh : Qh;
  _Float16* de = blockIdx.y ? Ke : Qe;
  float4 a = *(const float4*)&src[idx];
  float4 b = *(const float4*)&src[idx + 4];
  float v[8] = {a.x, a.y, a.z, a.w, b.x, b.y, b.z, b.w};
  half8 oh, oe;
#pragma unroll
  for (int t = 0; t < 8; ++t) {
    _Float16 hh = (_Float16)v[t];
    oh[t] = hh;
    oe[t] = (_Float16)(v[t] - (float)hh);
  }
  *(half8*)&dh[idx] = oh;
  *(half8*)&de[idx] = oe;
}

// ---------------- V -> Vt (transposed, fp16) ----------------
__global__ __launch_bounds__(256) void vt_kernel(const float* __restrict__ V,
                                                 _Float16* __restrict__ Vt) {
  __shared__ float tile[32][33];
  int h = blockIdx.z, dt = blockIdx.y, jt = blockIdx.x;
  int tx = threadIdx.x, ty = threadIdx.y;
  for (int k = 0; k < 4; ++k) {
    int row = jt * 32 + ty + k * 8;
    tile[ty + k * 8][tx] = V[((h * T_SEQ) + row) * HD + dt * 32 + tx];
  }
  __syncthreads();
  for (int k = 0; k < 4; ++k) {
    int d = dt * 32 + ty + k * 8;
    int j = jt * 32 + tx;
    Vt[((size_t)(h * HD) + d) * VT_STRIDE + j] = (_Float16)tile[tx][ty + k * 8];
  }
}

// ---------------- V column sums (for exactly-dead rows) ----------------
__global__ __launch_bounds__(256) void vsum_kernel(const float* __restrict__ V,
                                                   float* __restrict__ Vpart) {
  const int h = blockIdx.y, part = blockIdx.x;
  const int d = threadIdx.x & 127, half = threadIdx.x >> 7;
  float s = 0.f;
  for (int j = part * 1024 + half; j < part * 1024 + 1024; j += 2)
    s += V[(size_t)((h * T_SEQ) + j) * HD + d];
  __shared__ float red[2][128];
  red[half][d] = s;
  __syncthreads();
  if (threadIdx.x < 128)
    Vpart[(h * 4 + part) * 128 + threadIdx.x] = red[0][threadIdx.x] + red[1][threadIdx.x];
}

// ---------------- Kernel A: downsampled scores (fp32, bit-stable) ----------------
__global__ __launch_bounds__(256) void sds_kernel(const float* __restrict__ Q,
                                                  const float* __restrict__ K,
                                                  float* __restrict__ sds) {
  __shared__ float Qs[16][132];
  __shared__ float Ks[16][132];
  const int h = blockIdx.z;
  const int by = blockIdx.y, bx = blockIdx.x;
  const int tid = threadIdx.y * 16 + threadIdx.x;
  for (int t = tid; t < 512; t += 256) {
    int r = t >> 5, f = (t & 31) * 4;
    *(float4*)&Qs[r][f] = *(const float4*)&Q[((h * T_SEQ) + (by * 16 + r) * 8) * HD + f];
    *(float4*)&Ks[r][f] = *(const float4*)&K[((h * T_SEQ) + (bx * 16 + r) * 8) * HD + f];
  }
  __syncthreads();
  const int ty = threadIdx.y, tx = threadIdx.x;
  float acc = 0.0f;
  for (int k = 0; k < 32; ++k) {
    float4 a = *(float4*)&Qs[ty][k * 4];
    float4 b = *(float4*)&Ks[tx][k * 4];
    acc += a.x * b.x + a.y * b.y + a.z * b.z + a.w * b.w;
  }
  sds[((h * DS) + by * 16 + ty) * DS + bx * 16 + tx] = acc * SCALE;
}

// ---------------- Kernel B: exact 128th-largest per ds-row ----------------
__global__ __launch_bounds__(64) void thr_kernel(const float* __restrict__ sds,
                                                 float* __restrict__ thr) {
  const int row = blockIdx.x;
  const int lane = threadIdx.x;
  unsigned v[8];
  for (int t = 0; t < 8; ++t) {
    float f = sds[row * DS + t * 64 + lane];
    unsigned b = __float_as_uint(f);
    v[t] = (b & 0x80000000u) ? ~b : (b | 0x80000000u);
  }
  unsigned prefix = 0u;
  for (int bit = 31; bit >= 0; --bit) {
    unsigned cand = prefix | (1u << bit);
    int c = 0;
    for (int t = 0; t < 8; ++t) c += (v[t] >= cand) ? 1 : 0;
    for (int off = 32; off > 0; off >>= 1) c += __shfl_down(c, off, 64);
    c = __shfl(c, 0, 64);
    if (c >= 128) prefix = cand;
  }
  if (lane == 0) {
    unsigned b = (prefix & 0x80000000u) ? (prefix ^ 0x80000000u) : ~prefix;
    thr[row] = __uint_as_float(b);
  }
}

// ---------------- Kernel B2: per (h, row-tile16, chunk32) bias max ----------------
__global__ __launch_bounds__(256) void bmax_kernel(const float* __restrict__ sds,
                                                   const float* __restrict__ thr,
                                                   const float* __restrict__ U,
                                                   float* __restrict__ bmax16) {
  const int h = blockIdx.y, rt = blockIdx.x;
  const int tid = threadIdx.x, ww = tid >> 6, lane = tid & 63;
  const int r = lane >> 2, q = lane & 3;
  const int i = rt * 16 + r;
  float u = U[i];
  u = fminf(fmaxf(u, 0.0f), 1.0f);
  const float us = 1.0f + u;
  const int id = i >> 3;
  const float bb = us * thr[h * DS + id];
  const float* srow = &sds[((h * DS) + id) * DS];
  for (int c = ww; c < NCH; c += 4) {
    float sval = srow[(c << 2) + q];
    float a = us * sval;
    float bias = (1.0f - sigmoidf_((a - bb) * 10.0f)) * NEG9;
    for (int off = 1; off < 64; off <<= 1)
      bias = fmaxf(bias, __shfl_xor(bias, off, 64));
    if (lane == 0) bmax16[((h * NRT) + rt) * NCH + c] = bias;
  }
}

// ---------------- Kernel C: split-j MFMA flash attention ----------------
// Block = (seg, rt, h): 16 rows x 32-chunk j-segment. 4 waves, wave w owns
// chunks c = c0 + w + 4k. Writes partial (m,l,O) to global; reduce merges.
__global__ __launch_bounds__(256) void attn5_kernel(
    const _Float16* __restrict__ Qh, const _Float16* __restrict__ Qe,
    const _Float16* __restrict__ Kh, const _Float16* __restrict__ Ke,
    const _Float16* __restrict__ Vt, const float* __restrict__ U,
    const float* __restrict__ sds, const float* __restrict__ thr,
    const float* __restrict__ bmax16, float* __restrict__ partials) {
  const int seg = blockIdx.x, rt = blockIdx.y, h = blockIdx.z;
  const int ns = (rt >> 6) + 1;
  if (seg >= ns) return;
  const int i0 = rt * 16;
  const int nchunks = (rt >> 1) + 1;
  const int c0 = seg * SEGC;
  const int len = min(SEGC, nchunks - c0);  // >= 1

  const int tid = threadIdx.x;
  const int w = tid >> 6;
  const int lane = tid & 63;
  const int quad = lane >> 4;
  const int n = lane & 15;

  __shared__ float Obuf[4][16][128];
  __shared__ _Float16 Ps[4][16][32];
  __shared__ float mW[4][16], lW[4][16], esW[4][16];

  // per-row constants (rows quad*4+r); 4 rows of a quad share one ds-row
  const int myid = (i0 >> 3) + (quad >> 1);
  float us[4], bb[4];
  for (int r = 0; r < 4; ++r) {
    int i = i0 + quad * 4 + r;
    float u = U[i];
    u = fminf(fmaxf(u, 0.0f), 1.0f);
    us[r] = 1.0f + u;
    bb[r] = us[r] * thr[h * DS + myid];
  }

  // Q A-fragments, main + residual
  half8 qfh[4], qfe[4];
  {
    const size_t qoff = (size_t)((h * T_SEQ) + i0 + n) * HD + quad * 8;
#pragma unroll
    for (int d = 0; d < 4; ++d) {
      qfh[d] = *(const half8*)&Qh[qoff + d * 32];
      qfe[d] = *(const half8*)&Qe[qoff + d * 32];
    }
  }

  floatx4 acc[8];
  for (int t = 0; t < 8; ++t) acc[t] = (floatx4){0.f, 0.f, 0.f, 0.f};
  float m_[4], l_[4];
  for (int r = 0; r < 4; ++r) { m_[r] = -INFINITY; l_[r] = 0.0f; }

  // planning: candidates k -> chunk c0 + w + 4k
  const int nMine = (len > w) ? ((len - w + 3) >> 2) : 0;  // <= 8
  float bval = -3.0e38f;
  if (lane < nMine)
    bval = bmax16[((h * NRT) + rt) * NCH + c0 + w + (lane << 2)];
  const unsigned long long bits = (nMine > 0) ? ((1ull << nMine) - 1ull) : 0ull;
  const unsigned long long hotMask = __ballot(lane < nMine && bval > -124.0f) & bits;
  const unsigned long long nullMask = __ballot(lane < nMine && bval == NEG9) & bits;
  const unsigned long long coldMask = bits & ~hotMask & ~nullMask;
  // nullMask chunks: every score exactly -1e9f; alive-row weight <= e^-64 (ref too);
  // dead rows handled exactly in reduce via uniform-softmax closed form.

  for (int sweep = 0; sweep < 2; ++sweep) {
    unsigned long long mask = (sweep == 0) ? hotMask : coldMask;
    while (mask) {
      const int cc = __builtin_ctzll(mask);
      mask &= mask - 1ull;
      if (sweep == 1) {
        float bm16 = __shfl(bval, cc, 64);
        float mm = fminf(fminf(m_[0], m_[1]), fminf(m_[2], m_[3]));
        mm = fminf(mm, __shfl_xor(mm, 16, 64));
        mm = fminf(mm, __shfl_xor(mm, 32, 64));
        if (bm16 + 12.0f < mm - 40.0f) continue;  // contribution < e^-40 relative
      }
      const int c = c0 + w + (cc << 2);
      const int j0 = c * BN;

      // ---- bias: bit-identical fp32 sequence ----
      const int jdA = (c << 2) + (n >> 3);
      const float svA = sds[((h * DS) + myid) * DS + jdA];
      const float svB = sds[((h * DS) + myid) * DS + jdA + 2];
      float biasA[4], biasB[4];
      for (int r = 0; r < 4; ++r) {
        float aA = us[r] * svA;
        biasA[r] = (1.0f - sigmoidf_((aA - bb[r]) * 10.0f)) * NEG9;
        float aB = us[r] * svB;
        biasB[r] = (1.0f - sigmoidf_((aB - bb[r]) * 10.0f)) * NEG9;
      }

      // ---- K loads (both col-tiles, main + residual) ----
      const size_t kbase = (size_t)((h * T_SEQ) + j0 + n) * HD + quad * 8;
      half8 kh0[4], ke0[4], kh1[4], ke1[4];
#pragma unroll
      for (int d = 0; d < 4; ++d) {
        kh0[d] = *(const half8*)&Kh[kbase + d * 32];
        ke0[d] = *(const half8*)&Ke[kbase + d * 32];
        kh1[d] = *(const half8*)&Kh[kbase + 16 * HD + d * 32];
        ke1[d] = *(const half8*)&Ke[kbase + 16 * HD + d * 32];
      }

      // ---- QK^T: 3-term fp16 split, 24 mfma ----
      floatx4 S0 = (floatx4){0.f, 0.f, 0.f, 0.f};
      floatx4 S1 = (floatx4){0.f, 0.f, 0.f, 0.f};
#pragma unroll
      for (int d = 0; d < 4; ++d) {
        S0 = __builtin_amdgcn_mfma_f32_16x16x32_f16(qfh[d], kh0[d], S0, 0, 0, 0);
        S1 = __builtin_amdgcn_mfma_f32_16x16x32_f16(qfh[d], kh1[d], S1, 0, 0, 0);
      }
#pragma unroll
      for (int d = 0; d < 4; ++d) {
        S0 = __builtin_amdgcn_mfma_f32_16x16x32_f16(qfe[d], kh0[d], S0, 0, 0, 0);
        S1 = __builtin_amdgcn_mfma_f32_16x16x32_f16(qfe[d], kh1[d], S1, 0, 0, 0);
        S0 = __builtin_amdgcn_mfma_f32_16x16x32_f16(qfh[d], ke0[d], S0, 0, 0, 0);
        S1 = __builtin_amdgcn_mfma_f32_16x16x32_f16(qfh[d], ke1[d], S1, 0, 0, 0);
      }

      // ---- scores & online softmax ----
      const int jA = j0 + n, jB = j0 + 16 + n;
      float sc0[4], sc1[4];
      for (int r = 0; r < 4; ++r) {
        int i = i0 + quad * 4 + r;
        sc0[r] = (jA <= i) ? (S0[r] * SCALE + biasA[r]) : NEG9;
        sc1[r] = (jB <= i) ? (S1[r] * SCALE + biasB[r]) : NEG9;
      }
      float mx[4];
      for (int r = 0; r < 4; ++r) mx[r] = fmaxf(sc0[r], sc1[r]);
      for (int d = 1; d < 16; d <<= 1)
        for (int r = 0; r < 4; ++r) mx[r] = fmaxf(mx[r], __shfl_xor(mx[r], d, 64));
      float alpha[4], lsum[4];
      _Float16 ph0[4], ph1[4];
      for (int r = 0; r < 4; ++r) {
        float mnew = fmaxf(m_[r], mx[r]);
        alpha[r] = __expf(m_[r] - mnew);  // -inf -> 0
        ph0[r] = (_Float16)__expf(sc0[r] - mnew);
        ph1[r] = (_Float16)__expf(sc1[r] - mnew);
        lsum[r] = (float)ph0[r] + (float)ph1[r];  // l consistent with PV numerator
        m_[r] = mnew;
      }
      for (int d = 1; d < 16; d <<= 1)
        for (int r = 0; r < 4; ++r) lsum[r] += __shfl_xor(lsum[r], d, 64);
      for (int r = 0; r < 4; ++r) l_[r] = l_[r] * alpha[r] + lsum[r];
      for (int t = 0; t < 8; ++t)
        for (int r = 0; r < 4; ++r) acc[t][r] *= alpha[r];

      // ---- P: C-layout -> A-layout via wave-private LDS ----
      for (int r = 0; r < 4; ++r) {
        Ps[w][quad * 4 + r][n] = ph0[r];
        Ps[w][quad * 4 + r][n + 16] = ph1[r];
      }
      __builtin_amdgcn_sched_barrier(0);
      __builtin_amdgcn_s_waitcnt(0xC07F);  // lgkmcnt(0) only
      __builtin_amdgcn_sched_barrier(0);
      half8 pf = *(half8*)&Ps[w][n][quad * 8];

      // ---- P @ V ----
      const _Float16* vbase = &Vt[(size_t)((h * HD) + n) * VT_STRIDE + j0 + quad * 8];
#pragma unroll
      for (int t = 0; t < 8; ++t) {
        half8 vf = *(const half8*)&vbase[(size_t)t * 16 * VT_STRIDE];
        acc[t] = __builtin_amdgcn_mfma_f32_16x16x32_f16(pf, vf, acc[t], 0, 0, 0);
      }
    }
  }

  // ---- merge 4 waves, write partial (m, l, O) ----
  if (n == 0) {
    for (int r = 0; r < 4; ++r) {
      mW[w][quad * 4 + r] = m_[r];
      lW[w][quad * 4 + r] = l_[r];
    }
  }
  for (int t = 0; t < 8; ++t)
    for (int r = 0; r < 4; ++r) Obuf[w][quad * 4 + r][t * 16 + n] = acc[t][r];
  __syncthreads();

  float* pb = partials + (size_t)(h * NPART_H + tile_base(rt) + seg) * PART_F;
  if (tid < 16) {
    int r = tid;
    float M = fmaxf(fmaxf(mW[0][r], mW[1][r]), fmaxf(mW[2][r], mW[3][r]));
    float L = 0.f;
    for (int s = 0; s < 4; ++s) {
      float es = (M == -INFINITY) ? 0.0f : expf(mW[s][r] - M);  // exp(-inf-M)=0 safe
      esW[s][r] = es;
      L += lW[s][r] * es;
    }
    pb[r] = M;
    pb[16 + r] = L;
  }
  __syncthreads();
  for (int idx = tid; idx < 16 * 128; idx += 256) {
    int r = idx >> 7;
    float o = Obuf[0][r][idx & 127] * esW[0][r] + Obuf[1][r][idx & 127] * esW[1][r] +
              Obuf[2][r][idx & 127] * esW[2][r] + Obuf[3][r][idx & 127] * esW[3][r];
    pb[32 + idx] = o;
  }
}

// ---------------- Reduce: merge <=4 partials per tile, dead-row closed form ----------------
__global__ __launch_bounds__(256) void reduce_kernel(const float* __restrict__ partials,
                                                     const float* __restrict__ Vpart,
                                                     float* __restrict__ out) {
  const int rt = blockIdx.x, h = blockIdx.y;
  const int ns = (rt >> 6) + 1;
  const int tid = threadIdx.x;
  const float* pb0 = partials + (size_t)(h * NPART_H + tile_base(rt)) * PART_F;

  __shared__ float esS[4][16], LinvS[16], VsS[128];
  __shared__ int deadS[16];

  if (tid < 16) {
    int r = tid;
    float m[4], M = -INFINITY;
    for (int s = 0; s < ns; ++s) {
      m[s] = pb0[s * PART_F + r];
      M = fmaxf(M, m[s]);
    }
    int dead = (M < ALIVE_MIN) ? 1 : 0;  // covers exactly -1e9 and -inf
    deadS[r] = dead;
    float L = 0.f;
    for (int s = 0; s < ns; ++s) {
      float es = (dead || m[s] == -INFINITY) ? 0.0f : expf(m[s] - M);
      esS[s][r] = es;
      L += pb0[s * PART_F + 16 + r] * es;
    }
    LinvS[r] = dead ? 0.0f : (1.0f / L);
  }
  if (tid >= 128 && tid < 256) {
    int d = tid - 128;
    VsS[d] = Vpart[(h * 4 + 0) * 128 + d] + Vpart[(h * 4 + 1) * 128 + d] +
             Vpart[(h * 4 + 2) * 128 + d] + Vpart[(h * 4 + 3) * 128 + d];
  }
  __syncthreads();

  for (int idx = tid; idx < 16 * 128; idx += 256) {
    int r = idx >> 7, d = idx & 127;
    float o;
    if (deadS[r]) {
      o = VsS[d] * 0.000244140625f;  // exact 2^-12 scaling: uniform softmax over 4096
    } else {
      o = 0.f;
      for (int s = 0; s < ns; ++s) o += pb0[s * PART_F + 32 + idx] * esS[s][r];
      o *= LinvS[r];
    }
    out[(size_t)((h * T_SEQ) + rt * 16 + r) * HD + d] = o;
  }
}

extern "C" void kernel_launch(void* const* d_in, const int* in_sizes, int n_in,
                              void* d_out, int out_size, void* d_ws, size_t ws_size,
                              hipStream_t stream) {
  const float* Q = (const float*)d_in[0];
  const float* K = (const float*)d_in[1];
  const float* V = (const float*)d_in[2];
  const float* U = (const float*)d_in[3];
  float* out = (float*)d_out;

  char* wsb = (char*)d_ws;
  float* sds = (float*)wsb;                                        // 4 MB
  float* thr = (float*)(wsb + 4194304);                            // 8 KB
  float* bmax16 = (float*)(wsb + 4194304 + 8192);                  // 512 KB
  float* Vpart = (float*)(wsb + 4194304 + 8192 + 524288);          // 8 KB
  _Float16* Qh = (_Float16*)(wsb + 4194304 + 8192 + 524288 + 8192);
  _Float16* Qe = Qh + 2097152;
  _Float16* Kh = Qe + 2097152;
  _Float16* Ke = Kh + 2097152;
  _Float16* Vt = Ke + 2097152;                                     // 5 x 4 MB
  float* partials = (float*)((char*)(Vt + 2097152));               // 21.3 MB -> ~46 MB total

  const int nQK = NH * T_SEQ * HD;  // 2,097,152
  cvt2_kernel<<<dim3(nQK / 2048, 2), 256, 0, stream>>>(Q, K, Qh, Qe, Kh, Ke, nQK);
  vt_kernel<<<dim3(T_SEQ / 32, HD / 32, NH), dim3(32, 8), 0, stream>>>(V, Vt);
  vsum_kernel<<<dim3(4, NH), 256, 0, stream>>>(V, Vpart);

  sds_kernel<<<dim3(DS / 16, DS / 16, NH), dim3(16, 16), 0, stream>>>(Q, K, sds);
  thr_kernel<<<NH * DS, 64, 0, stream>>>(sds, thr);
  bmax_kernel<<<dim3(NRT, NH), 256, 0, stream>>>(sds, thr, U, bmax16);

  attn5_kernel<<<dim3(4, NRT, NH), 256, 0, stream>>>(Qh, Qe, Kh, Ke, Vt, U, sds, thr,
                                                     bmax16, partials);
  reduce_kernel<<<dim3(NRT, NH), 256, 0, stream>>>(partials, Vpart, out);
}